// Round 1
// baseline (606.848 us; speedup 1.0000x reference)
//
#include <hip/hip_runtime.h>
#include <hip/hip_bf16.h>

#define IN_C 128
#define HID 64
#define HEADS 4
#define OUT_C 64
#define NEG_SLOPE 0.2f

// ---------------------------------------------------------------------------
// Tiled fp32 GEMM: C[M,N] = A[M,K] @ B[K,N]. BM=BN=BK=64, 256 threads,
// 4x4 outputs/thread. A staged transposed in LDS so inner loop is 2x
// ds_read_b128 + 16 fma per thread per k-step.
// ---------------------------------------------------------------------------
template <int BM, int BN, int BK>
__global__ __launch_bounds__(256) void gemm_kernel(
    const float* __restrict__ A, const float* __restrict__ B,
    float* __restrict__ C, int M, int N, int K) {
  __shared__ float As[BK][BM + 4];  // transposed: As[k][m]
  __shared__ float Bs[BK][BN + 4];  // Bs[k][n]
  const int t = threadIdx.x;
  const int tx = t % 16, ty = t / 16;
  const int bm = blockIdx.x * BM;
  const int bn = blockIdx.y * BN;
  float acc[4][4] = {};

  for (int k0 = 0; k0 < K; k0 += BK) {
    constexpr int A_ITERS = (BM * BK) / (4 * 256);
#pragma unroll
    for (int i = 0; i < A_ITERS; ++i) {
      int flat = t + i * 256;       // float4 index in BM x (BK/4) grid
      int row = flat / (BK / 4);
      int kg = flat % (BK / 4);
      float4 v = make_float4(0.f, 0.f, 0.f, 0.f);
      int gr = bm + row;
      if (gr < M)
        v = *reinterpret_cast<const float4*>(&A[(size_t)gr * K + k0 + kg * 4]);
      As[kg * 4 + 0][row] = v.x;
      As[kg * 4 + 1][row] = v.y;
      As[kg * 4 + 2][row] = v.z;
      As[kg * 4 + 3][row] = v.w;
    }
    constexpr int B_ITERS = (BK * BN) / (4 * 256);
#pragma unroll
    for (int i = 0; i < B_ITERS; ++i) {
      int flat = t + i * 256;
      int krow = flat / (BN / 4);
      int cg = flat % (BN / 4);
      float4 v = *reinterpret_cast<const float4*>(
          &B[(size_t)(k0 + krow) * N + bn + cg * 4]);
      *reinterpret_cast<float4*>(&Bs[krow][cg * 4]) = v;
    }
    __syncthreads();
#pragma unroll
    for (int k = 0; k < BK; ++k) {
      float4 a4 = *reinterpret_cast<const float4*>(&As[k][ty * 4]);
      float4 b4 = *reinterpret_cast<const float4*>(&Bs[k][tx * 4]);
      float av[4] = {a4.x, a4.y, a4.z, a4.w};
      float bv[4] = {b4.x, b4.y, b4.z, b4.w};
#pragma unroll
      for (int i = 0; i < 4; ++i)
#pragma unroll
        for (int j = 0; j < 4; ++j) acc[i][j] += av[i] * bv[j];
    }
    __syncthreads();
  }
#pragma unroll
  for (int i = 0; i < 4; ++i) {
    int gr = bm + ty * 4 + i;
    if (gr < M) {
      float4 v = make_float4(acc[i][0], acc[i][1], acc[i][2], acc[i][3]);
      *reinterpret_cast<float4*>(&C[(size_t)gr * N + bn + tx * 4]) = v;
    }
  }
}

// ---------------------------------------------------------------------------
// Layer-1 attention coefficients: one wave per node.
// a_src[n,h] = dot(h1[n,h,:], att_src[h,:]); same for a_dst.
// Lane l holds channels 4l..4l+3 (head = l>>4).
// ---------------------------------------------------------------------------
__global__ __launch_bounds__(256) void attn1_kernel(
    const float* __restrict__ h1, const float* __restrict__ att_src,
    const float* __restrict__ att_dst, float* __restrict__ a_src,
    float* __restrict__ a_dst, int n_nodes) {
  int wave = (int)((blockIdx.x * blockDim.x + threadIdx.x) >> 6);
  int lane = threadIdx.x & 63;
  if (wave >= n_nodes) return;
  float4 h4 = *reinterpret_cast<const float4*>(&h1[(size_t)wave * 256 + lane * 4]);
  float4 s4 = *reinterpret_cast<const float4*>(&att_src[lane * 4]);
  float4 d4 = *reinterpret_cast<const float4*>(&att_dst[lane * 4]);
  float vs = h4.x * s4.x + h4.y * s4.y + h4.z * s4.z + h4.w * s4.w;
  float vd = h4.x * d4.x + h4.y * d4.y + h4.z * d4.z + h4.w * d4.w;
#pragma unroll
  for (int m = 1; m < 16; m <<= 1) {
    vs += __shfl_xor(vs, m);
    vd += __shfl_xor(vd, m);
  }
  if ((lane & 15) == 0) {
    a_src[wave * 4 + (lane >> 4)] = vs;
    a_dst[wave * 4 + (lane >> 4)] = vd;
  }
}

// Layer-2: single head, a_src[n] = dot(h2[n,:], att_src[0,:]).
__global__ __launch_bounds__(256) void attn2_kernel(
    const float* __restrict__ h2, const float* __restrict__ att_src,
    const float* __restrict__ att_dst, float* __restrict__ a_src,
    float* __restrict__ a_dst, int n_nodes) {
  int wave = (int)((blockIdx.x * blockDim.x + threadIdx.x) >> 6);
  int lane = threadIdx.x & 63;
  if (wave >= n_nodes) return;
  float h = h2[(size_t)wave * 64 + lane];
  float vs = h * att_src[lane];
  float vd = h * att_dst[lane];
#pragma unroll
  for (int m = 1; m < 64; m <<= 1) {
    vs += __shfl_xor(vs, m);
    vd += __shfl_xor(vd, m);
  }
  if (lane == 0) {
    a_src[wave] = vs;
    a_dst[wave] = vd;
  }
}

// ---------------------------------------------------------------------------
// CSR build: histogram -> single-block scan -> scatter.
// ---------------------------------------------------------------------------
__global__ void hist_kernel(const int* __restrict__ dst, int E,
                            int* __restrict__ deg) {
  int e = blockIdx.x * blockDim.x + threadIdx.x;
  if (e < E) atomicAdd(&deg[dst[e]], 1);
}

__global__ __launch_bounds__(1024) void scan_kernel(
    const int* __restrict__ deg, int n, int* __restrict__ offsets,
    int* __restrict__ cursor) {
  __shared__ int partial[1024];
  int t = threadIdx.x;
  int per = (n + 1023) / 1024;
  int start = t * per;
  int end = min(start + per, n);
  int sum = 0;
  for (int i = start; i < end; ++i) sum += deg[i];
  partial[t] = sum;
  __syncthreads();
  for (int off = 1; off < 1024; off <<= 1) {
    int v = (t >= off) ? partial[t - off] : 0;
    __syncthreads();
    partial[t] += v;
    __syncthreads();
  }
  int run = (t > 0) ? partial[t - 1] : 0;
  for (int i = start; i < end; ++i) {
    offsets[i] = run;
    cursor[i] = run;
    run += deg[i];
  }
}

__global__ void scatter_kernel(const int* __restrict__ src,
                               const int* __restrict__ dst, int E,
                               int* __restrict__ cursor,
                               int* __restrict__ ssrc) {
  int e = blockIdx.x * blockDim.x + threadIdx.x;
  if (e < E) {
    int d = dst[e];
    int pos = atomicAdd(&cursor[d], 1);
    ssrc[pos] = src[e];
  }
}

// ---------------------------------------------------------------------------
// Layer-1 aggregation: one wave per dst node, online softmax per head,
// channel-parallel across lanes (lane l -> channels 4l..4l+3, head l>>4).
// Applies bias + ELU, writes hact[n,256].
// ---------------------------------------------------------------------------
__global__ __launch_bounds__(256) void agg1_kernel(
    const float* __restrict__ h1, const float* __restrict__ a_src,
    const float* __restrict__ a_dst, const int* __restrict__ offsets,
    const int* __restrict__ deg, const int* __restrict__ ssrc,
    const float* __restrict__ bias, float* __restrict__ out, int n_nodes) {
  int wave = (int)((blockIdx.x * blockDim.x + threadIdx.x) >> 6);
  int lane = threadIdx.x & 63;
  if (wave >= n_nodes) return;
  int head = lane >> 4;
  int start = offsets[wave];
  int cnt = deg[wave];
  float ad = a_dst[wave * 4 + head];
  float m = -1e30f, l = 0.f;
  float acc0 = 0.f, acc1 = 0.f, acc2 = 0.f, acc3 = 0.f;
  for (int j = 0; j < cnt; ++j) {
    int s = ssrc[start + j];
    float as = a_src[s * 4 + head];
    float e = as + ad;
    e = (e > 0.f) ? e : NEG_SLOPE * e;
    float mn = fmaxf(m, e);
    float scale = __expf(m - mn);
    float p = __expf(e - mn);
    m = mn;
    l = l * scale + p;
    float4 h4 = *reinterpret_cast<const float4*>(&h1[(size_t)s * 256 + lane * 4]);
    acc0 = acc0 * scale + p * h4.x;
    acc1 = acc1 * scale + p * h4.y;
    acc2 = acc2 * scale + p * h4.z;
    acc3 = acc3 * scale + p * h4.w;
  }
  float inv = 1.0f / l;
  int col = lane * 4;
  float4 b4 = *reinterpret_cast<const float4*>(&bias[col]);
  float o0 = acc0 * inv + b4.x;
  float o1 = acc1 * inv + b4.y;
  float o2 = acc2 * inv + b4.z;
  float o3 = acc3 * inv + b4.w;
  o0 = o0 > 0.f ? o0 : __expf(o0) - 1.f;
  o1 = o1 > 0.f ? o1 : __expf(o1) - 1.f;
  o2 = o2 > 0.f ? o2 : __expf(o2) - 1.f;
  o3 = o3 > 0.f ? o3 : __expf(o3) - 1.f;
  float4 ov = make_float4(o0, o1, o2, o3);
  *reinterpret_cast<float4*>(&out[(size_t)wave * 256 + col]) = ov;
}

// Layer-2 aggregation: one wave per node, 1 head, lane = channel. Adds bias.
__global__ __launch_bounds__(256) void agg2_kernel(
    const float* __restrict__ h2, const float* __restrict__ a_src,
    const float* __restrict__ a_dst, const int* __restrict__ offsets,
    const int* __restrict__ deg, const int* __restrict__ ssrc,
    const float* __restrict__ bias, float* __restrict__ out, int n_nodes) {
  int wave = (int)((blockIdx.x * blockDim.x + threadIdx.x) >> 6);
  int lane = threadIdx.x & 63;
  if (wave >= n_nodes) return;
  int start = offsets[wave];
  int cnt = deg[wave];
  float ad = a_dst[wave];
  float m = -1e30f, l = 0.f, acc = 0.f;
  for (int j = 0; j < cnt; ++j) {
    int s = ssrc[start + j];
    float as = a_src[s];
    float e = as + ad;
    e = (e > 0.f) ? e : NEG_SLOPE * e;
    float mn = fmaxf(m, e);
    float scale = __expf(m - mn);
    float p = __expf(e - mn);
    m = mn;
    l = l * scale + p;
    acc = acc * scale + p * h2[(size_t)s * 64 + lane];
  }
  out[(size_t)wave * 64 + lane] = acc / l + bias[lane];
}

// ---------------------------------------------------------------------------
extern "C" void kernel_launch(void* const* d_in, const int* in_sizes, int n_in,
                              void* d_out, int out_size, void* d_ws,
                              size_t ws_size, hipStream_t stream) {
  const float* x = (const float*)d_in[0];
  const int* edge_index = (const int*)d_in[1];
  const float* W1 = (const float*)d_in[2];
  const float* att_src1 = (const float*)d_in[3];
  const float* att_dst1 = (const float*)d_in[4];
  const float* b1 = (const float*)d_in[5];
  const float* W2 = (const float*)d_in[6];
  const float* att_src2 = (const float*)d_in[7];
  const float* att_dst2 = (const float*)d_in[8];
  const float* b2 = (const float*)d_in[9];

  const int n = in_sizes[0] / IN_C;       // 50000
  const int E = in_sizes[1] / 2;          // 850000
  const int* src = edge_index;
  const int* dst = edge_index + E;

  // Workspace carve (256B-aligned slices).
  char* ws = (char*)d_ws;
  size_t off = 0;
  auto carve = [&](size_t bytes) -> void* {
    void* p = ws + off;
    off = (off + bytes + 255) & ~(size_t)255;
    return p;
  };
  float* h1 = (float*)carve((size_t)n * 256 * 4);
  float* hact = (float*)carve((size_t)n * 256 * 4);
  float* as1 = (float*)carve((size_t)n * 4 * 4);
  float* ad1 = (float*)carve((size_t)n * 4 * 4);
  int* deg = (int*)carve((size_t)n * 4);
  int* offsets = (int*)carve((size_t)n * 4);
  int* cursor = (int*)carve((size_t)n * 4);
  int* ssrc = (int*)carve((size_t)E * 4);
  // h2 / as2 / ad2 overlay h1 / as1 / ad1 (dead after agg1+gemm2 boundary).
  float* h2 = h1;      // [n,64] <= [n,256] region; h1 dead once gemm2 input is hact
  float* as2 = as1;
  float* ad2 = ad1;

  hipMemsetAsync(deg, 0, (size_t)n * 4, stream);

  // GEMM1: h1 = x @ W1   [n,128]@[128,256]
  {
    dim3 g((n + 63) / 64, (HEADS * HID) / 64);
    gemm_kernel<64, 64, 64><<<g, 256, 0, stream>>>(x, W1, h1, n, HEADS * HID, IN_C);
  }
  // attention coefficients layer 1
  attn1_kernel<<<(n * 64 + 255) / 256, 256, 0, stream>>>(h1, att_src1, att_dst1,
                                                         as1, ad1, n);
  // CSR build
  hist_kernel<<<(E + 255) / 256, 256, 0, stream>>>(dst, E, deg);
  scan_kernel<<<1, 1024, 0, stream>>>(deg, n, offsets, cursor);
  scatter_kernel<<<(E + 255) / 256, 256, 0, stream>>>(src, dst, E, cursor, ssrc);
  // aggregation layer 1 (+bias+ELU) -> hact
  agg1_kernel<<<(n * 64 + 255) / 256, 256, 0, stream>>>(h1, as1, ad1, offsets,
                                                        deg, ssrc, b1, hact, n);
  // GEMM2: h2 = hact @ W2   [n,256]@[256,64]   (h2 overlays h1 - h1 now dead)
  {
    dim3 g((n + 63) / 64, OUT_C / 64);
    gemm_kernel<64, 64, 64><<<g, 256, 0, stream>>>(hact, W2, h2, n, OUT_C,
                                                   HEADS * HID);
  }
  // attention coefficients layer 2
  attn2_kernel<<<(n * 64 + 255) / 256, 256, 0, stream>>>(h2, att_src2, att_dst2,
                                                         as2, ad2, n);
  // aggregation layer 2 (+bias) -> d_out
  agg2_kernel<<<(n * 64 + 255) / 256, 256, 0, stream>>>(
      h2, as2, ad2, offsets, deg, ssrc, b2, (float*)d_out, n);
}

// Round 2
// 457.887 us; speedup vs baseline: 1.3253x; 1.3253x over previous
//
#include <hip/hip_runtime.h>
#include <hip/hip_bf16.h>

#define IN_C 128
#define HID 64
#define HEADS 4
#define OUT_C 64
#define NEG_SLOPE 0.2f

__device__ __forceinline__ float bf16u_to_f(unsigned short u) {
  return __uint_as_float(((unsigned)u) << 16);
}

// ---------------------------------------------------------------------------
// Tiled fp32 GEMM + fused attention-coefficient epilogue.
// C-tile 64x64, 256 threads, 4x4 acc/thread. Writes H as bf16, and
// a_src[r,head] / a_dst[r,head] (fp32, from fp32 accumulators).
// blockIdx.y == head (BN=64 == channels per head for both layers).
// ---------------------------------------------------------------------------
template <int HEADS_T>
__global__ __launch_bounds__(256) void gemm_attn_kernel(
    const float* __restrict__ A, const float* __restrict__ B,
    const float* __restrict__ att_src, const float* __restrict__ att_dst,
    __hip_bfloat16* __restrict__ Hout, float* __restrict__ a_src,
    float* __restrict__ a_dst, int M, int N, int K) {
  constexpr int BM = 64, BN = 64, BK = 64;
  __shared__ float As[BK][BM + 4];  // transposed: As[k][m]
  __shared__ float Bs[BK][BN + 4];  // Bs[k][n]
  const int t = threadIdx.x;
  const int tx = t % 16, ty = t / 16;
  const int bm = blockIdx.x * BM;
  const int bn = blockIdx.y * BN;
  const int head = blockIdx.y;
  float acc[4][4] = {};

  for (int k0 = 0; k0 < K; k0 += BK) {
    constexpr int A_ITERS = (BM * BK) / (4 * 256);
#pragma unroll
    for (int i = 0; i < A_ITERS; ++i) {
      int flat = t + i * 256;
      int row = flat / (BK / 4);
      int kg = flat % (BK / 4);
      float4 v = make_float4(0.f, 0.f, 0.f, 0.f);
      int gr = bm + row;
      if (gr < M)
        v = *reinterpret_cast<const float4*>(&A[(size_t)gr * K + k0 + kg * 4]);
      As[kg * 4 + 0][row] = v.x;
      As[kg * 4 + 1][row] = v.y;
      As[kg * 4 + 2][row] = v.z;
      As[kg * 4 + 3][row] = v.w;
    }
    constexpr int B_ITERS = (BK * BN) / (4 * 256);
#pragma unroll
    for (int i = 0; i < B_ITERS; ++i) {
      int flat = t + i * 256;
      int krow = flat / (BN / 4);
      int cg = flat % (BN / 4);
      float4 v = *reinterpret_cast<const float4*>(
          &B[(size_t)(k0 + krow) * N + bn + cg * 4]);
      *reinterpret_cast<float4*>(&Bs[krow][cg * 4]) = v;
    }
    __syncthreads();
#pragma unroll
    for (int k = 0; k < BK; ++k) {
      float4 a4 = *reinterpret_cast<const float4*>(&As[k][ty * 4]);
      float4 b4 = *reinterpret_cast<const float4*>(&Bs[k][tx * 4]);
      float av[4] = {a4.x, a4.y, a4.z, a4.w};
      float bv[4] = {b4.x, b4.y, b4.z, b4.w};
#pragma unroll
      for (int i = 0; i < 4; ++i)
#pragma unroll
        for (int j = 0; j < 4; ++j) acc[i][j] += av[i] * bv[j];
    }
    __syncthreads();
  }

  // Epilogue: bf16 H store + fused attention dot products.
  float4 s4 = *reinterpret_cast<const float4*>(&att_src[head * 64 + tx * 4]);
  float4 d4 = *reinterpret_cast<const float4*>(&att_dst[head * 64 + tx * 4]);
#pragma unroll
  for (int i = 0; i < 4; ++i) {
    int gr = bm + ty * 4 + i;
    float ps = acc[i][0] * s4.x + acc[i][1] * s4.y + acc[i][2] * s4.z +
               acc[i][3] * s4.w;
    float pd = acc[i][0] * d4.x + acc[i][1] * d4.y + acc[i][2] * d4.z +
               acc[i][3] * d4.w;
#pragma unroll
    for (int m = 1; m < 16; m <<= 1) {
      ps += __shfl_xor(ps, m);
      pd += __shfl_xor(pd, m);
    }
    if (gr < M) {
      __hip_bfloat16 hb[4];
#pragma unroll
      for (int j = 0; j < 4; ++j) hb[j] = __float2bfloat16(acc[i][j]);
      *reinterpret_cast<ushort4*>(&Hout[(size_t)gr * N + bn + tx * 4]) =
          *reinterpret_cast<const ushort4*>(hb);
      if (tx == 0) {
        a_src[(size_t)gr * HEADS_T + head] = ps;
        a_dst[(size_t)gr * HEADS_T + head] = pd;
      }
    }
  }
}

// ---------------------------------------------------------------------------
// CSR build: histogram -> 3-stage hierarchical scan -> scatter.
// ---------------------------------------------------------------------------
__global__ void hist_kernel(const int* __restrict__ dst, int E,
                            int* __restrict__ deg) {
  int e = blockIdx.x * blockDim.x + threadIdx.x;
  if (e < E) atomicAdd(&deg[dst[e]], 1);
}

__global__ __launch_bounds__(256) void scan_partial_kernel(
    const int* __restrict__ deg, int n, int* __restrict__ partials) {
  __shared__ int sm[256];
  int t = threadIdx.x;
  int i = blockIdx.x * 256 + t;
  sm[t] = (i < n) ? deg[i] : 0;
  __syncthreads();
  for (int off = 128; off > 0; off >>= 1) {
    if (t < off) sm[t] += sm[t + off];
    __syncthreads();
  }
  if (t == 0) partials[blockIdx.x] = sm[0];
}

__global__ __launch_bounds__(256) void scan_base_kernel(
    const int* __restrict__ partials, int nb, int* __restrict__ base) {
  __shared__ int sm[256];
  int t = threadIdx.x;
  int v = (t < nb) ? partials[t] : 0;
  sm[t] = v;
  __syncthreads();
  for (int off = 1; off < 256; off <<= 1) {
    int u = (t >= off) ? sm[t - off] : 0;
    __syncthreads();
    sm[t] += u;
    __syncthreads();
  }
  if (t < nb) base[t] = sm[t] - v;  // exclusive prefix
}

__global__ __launch_bounds__(256) void scan_expand_kernel(
    const int* __restrict__ deg, int n, const int* __restrict__ base,
    int* __restrict__ offsets, int* __restrict__ cursor) {
  __shared__ int sm[256];
  int t = threadIdx.x;
  int i = blockIdx.x * 256 + t;
  int v = (i < n) ? deg[i] : 0;
  sm[t] = v;
  __syncthreads();
  for (int off = 1; off < 256; off <<= 1) {
    int u = (t >= off) ? sm[t - off] : 0;
    __syncthreads();
    sm[t] += u;
    __syncthreads();
  }
  int excl = sm[t] - v + base[blockIdx.x];
  if (i < n) {
    offsets[i] = excl;
    cursor[i] = excl;
  }
}

__global__ void scatter_kernel(const int* __restrict__ src,
                               const int* __restrict__ dst, int E,
                               int* __restrict__ cursor,
                               int* __restrict__ ssrc) {
  int e = blockIdx.x * blockDim.x + threadIdx.x;
  if (e < E) {
    int d = dst[e];
    int pos = atomicAdd(&cursor[d], 1);
    ssrc[pos] = src[e];
  }
}

// ---------------------------------------------------------------------------
// Layer-1 aggregation: one wave per dst node. Direct exp (no max shift --
// |e| <= ~3 so safe). Lane l -> channels 4l..4l+3 (head = l>>4).
// bf16 gather of h1, fp32 accumulate; +bias +ELU -> hact fp32.
// ---------------------------------------------------------------------------
__global__ __launch_bounds__(256) void agg1_kernel(
    const __hip_bfloat16* __restrict__ h1, const float* __restrict__ a_src,
    const float* __restrict__ a_dst, const int* __restrict__ offsets,
    const int* __restrict__ deg, const int* __restrict__ ssrc,
    const float* __restrict__ bias, float* __restrict__ out, int n_nodes) {
  int wave = (int)((blockIdx.x * blockDim.x + threadIdx.x) >> 6);
  int lane = threadIdx.x & 63;
  if (wave >= n_nodes) return;
  int head = lane >> 4;
  int start = offsets[wave];
  int cnt = deg[wave];
  float ad = a_dst[wave * 4 + head];
  float l = 0.f;
  float acc0 = 0.f, acc1 = 0.f, acc2 = 0.f, acc3 = 0.f;
  int s = (cnt > 0) ? ssrc[start] : 0;
  for (int j = 0; j < cnt; ++j) {
    int snext = (j + 1 < cnt) ? ssrc[start + j + 1] : 0;
    float e = a_src[s * 4 + head] + ad;
    e = (e > 0.f) ? e : NEG_SLOPE * e;
    float p = __expf(e);
    l += p;
    ushort4 h4 =
        *reinterpret_cast<const ushort4*>(&h1[(size_t)s * 256 + lane * 4]);
    acc0 += p * bf16u_to_f(h4.x);
    acc1 += p * bf16u_to_f(h4.y);
    acc2 += p * bf16u_to_f(h4.z);
    acc3 += p * bf16u_to_f(h4.w);
    s = snext;
  }
  float inv = 1.0f / l;
  int col = lane * 4;
  float4 b4 = *reinterpret_cast<const float4*>(&bias[col]);
  float o0 = acc0 * inv + b4.x;
  float o1 = acc1 * inv + b4.y;
  float o2 = acc2 * inv + b4.z;
  float o3 = acc3 * inv + b4.w;
  o0 = o0 > 0.f ? o0 : __expf(o0) - 1.f;
  o1 = o1 > 0.f ? o1 : __expf(o1) - 1.f;
  o2 = o2 > 0.f ? o2 : __expf(o2) - 1.f;
  o3 = o3 > 0.f ? o3 : __expf(o3) - 1.f;
  *reinterpret_cast<float4*>(&out[(size_t)wave * 256 + col]) =
      make_float4(o0, o1, o2, o3);
}

// Layer-2 aggregation: one wave per node, lane = channel; bf16 h2 gather.
__global__ __launch_bounds__(256) void agg2_kernel(
    const __hip_bfloat16* __restrict__ h2, const float* __restrict__ a_src,
    const float* __restrict__ a_dst, const int* __restrict__ offsets,
    const int* __restrict__ deg, const int* __restrict__ ssrc,
    const float* __restrict__ bias, float* __restrict__ out, int n_nodes) {
  int wave = (int)((blockIdx.x * blockDim.x + threadIdx.x) >> 6);
  int lane = threadIdx.x & 63;
  if (wave >= n_nodes) return;
  int start = offsets[wave];
  int cnt = deg[wave];
  float ad = a_dst[wave];
  float l = 0.f, acc = 0.f;
  int s = (cnt > 0) ? ssrc[start] : 0;
  for (int j = 0; j < cnt; ++j) {
    int snext = (j + 1 < cnt) ? ssrc[start + j + 1] : 0;
    float e = a_src[s] + ad;
    e = (e > 0.f) ? e : NEG_SLOPE * e;
    float p = __expf(e);
    l += p;
    acc += p * bf16u_to_f(((const unsigned short*)h2)[(size_t)s * 64 + lane]);
    s = snext;
  }
  out[(size_t)wave * 64 + lane] = acc / l + bias[lane];
}

// ---------------------------------------------------------------------------
extern "C" void kernel_launch(void* const* d_in, const int* in_sizes, int n_in,
                              void* d_out, int out_size, void* d_ws,
                              size_t ws_size, hipStream_t stream) {
  const float* x = (const float*)d_in[0];
  const int* edge_index = (const int*)d_in[1];
  const float* W1 = (const float*)d_in[2];
  const float* att_src1 = (const float*)d_in[3];
  const float* att_dst1 = (const float*)d_in[4];
  const float* b1 = (const float*)d_in[5];
  const float* W2 = (const float*)d_in[6];
  const float* att_src2 = (const float*)d_in[7];
  const float* att_dst2 = (const float*)d_in[8];
  const float* b2 = (const float*)d_in[9];

  const int n = in_sizes[0] / IN_C;  // 50000
  const int E = in_sizes[1] / 2;     // 850000
  const int* src = edge_index;
  const int* dst = edge_index + E;
  const int nb = (n + 255) / 256;  // scan chunks (196)

  char* ws = (char*)d_ws;
  size_t off = 0;
  auto carve = [&](size_t bytes) -> void* {
    void* p = ws + off;
    off = (off + bytes + 255) & ~(size_t)255;
    return p;
  };
  __hip_bfloat16* h1b = (__hip_bfloat16*)carve((size_t)n * 256 * 2);
  float* hact = (float*)carve((size_t)n * 256 * 4);
  __hip_bfloat16* h2b = (__hip_bfloat16*)carve((size_t)n * 64 * 2);
  float* as1 = (float*)carve((size_t)n * 4 * 4);
  float* ad1 = (float*)carve((size_t)n * 4 * 4);
  float* as2 = (float*)carve((size_t)n * 4);
  float* ad2 = (float*)carve((size_t)n * 4);
  int* deg = (int*)carve((size_t)n * 4);
  int* offsets = (int*)carve((size_t)n * 4);
  int* cursor = (int*)carve((size_t)n * 4);
  int* ssrc = (int*)carve((size_t)E * 4);
  int* partials = (int*)carve((size_t)nb * 4);
  int* base = (int*)carve((size_t)nb * 4);

  hipMemsetAsync(deg, 0, (size_t)n * 4, stream);

  // GEMM1 + attn1 fused: h1b(bf16) = x @ W1; as1/ad1 from fp32 acc.
  {
    dim3 g((n + 63) / 64, (HEADS * HID) / 64);
    gemm_attn_kernel<HEADS><<<g, 256, 0, stream>>>(
        x, W1, att_src1, att_dst1, h1b, as1, ad1, n, HEADS * HID, IN_C);
  }
  // CSR build
  hist_kernel<<<(E + 255) / 256, 256, 0, stream>>>(dst, E, deg);
  scan_partial_kernel<<<nb, 256, 0, stream>>>(deg, n, partials);
  scan_base_kernel<<<1, 256, 0, stream>>>(partials, nb, base);
  scan_expand_kernel<<<nb, 256, 0, stream>>>(deg, n, base, offsets, cursor);
  scatter_kernel<<<(E + 255) / 256, 256, 0, stream>>>(src, dst, E, cursor, ssrc);
  // aggregation layer 1 (+bias+ELU) -> hact
  agg1_kernel<<<(n * 64 + 255) / 256, 256, 0, stream>>>(h1b, as1, ad1, offsets,
                                                        deg, ssrc, b1, hact, n);
  // GEMM2 + attn2 fused: h2b(bf16) = hact @ W2; as2/ad2.
  {
    dim3 g((n + 63) / 64, OUT_C / 64);
    gemm_attn_kernel<1><<<g, 256, 0, stream>>>(
        hact, W2, att_src2, att_dst2, h2b, as2, ad2, n, OUT_C, HEADS * HID);
  }
  // aggregation layer 2 (+bias) -> d_out
  agg2_kernel<<<(n * 64 + 255) / 256, 256, 0, stream>>>(
      h2b, as2, ad2, offsets, deg, ssrc, b2, (float*)d_out, n);
}

// Round 3
// 406.885 us; speedup vs baseline: 1.4914x; 1.1253x over previous
//
#include <hip/hip_runtime.h>
#include <hip/hip_bf16.h>

#define IN_C 128
#define HID 64
#define HEADS 4
#define OUT_C 64
#define NEG_SLOPE 0.2f

typedef __attribute__((ext_vector_type(8))) short bfrag8;   // 8 bf16 (4 VGPR)
typedef __attribute__((ext_vector_type(4))) float facc4;    // mfma C/D

__device__ __forceinline__ float bf16u_to_f(unsigned short u) {
  return __uint_as_float(((unsigned)u) << 16);
}

// ---------------------------------------------------------------------------
// x (fp32) -> bf16, 8 elems/thread.
// ---------------------------------------------------------------------------
__global__ __launch_bounds__(256) void cvt_bf16_kernel(
    const float* __restrict__ in, unsigned short* __restrict__ out, int n8) {
  int i = blockIdx.x * blockDim.x + threadIdx.x;
  if (i >= n8) return;
  float4 v0 = *reinterpret_cast<const float4*>(&in[(size_t)i * 8]);
  float4 v1 = *reinterpret_cast<const float4*>(&in[(size_t)i * 8 + 4]);
  unsigned short q[8];
  q[0] = __bfloat16_as_ushort(__float2bfloat16(v0.x));
  q[1] = __bfloat16_as_ushort(__float2bfloat16(v0.y));
  q[2] = __bfloat16_as_ushort(__float2bfloat16(v0.z));
  q[3] = __bfloat16_as_ushort(__float2bfloat16(v0.w));
  q[4] = __bfloat16_as_ushort(__float2bfloat16(v1.x));
  q[5] = __bfloat16_as_ushort(__float2bfloat16(v1.y));
  q[6] = __bfloat16_as_ushort(__float2bfloat16(v1.z));
  q[7] = __bfloat16_as_ushort(__float2bfloat16(v1.w));
  *reinterpret_cast<uint4*>(&out[(size_t)i * 8]) =
      *reinterpret_cast<const uint4*>(q);
}

// ---------------------------------------------------------------------------
// MFMA bf16 GEMM (64x64x64 tile, 4 waves, 16x16x32 mfma) + fused attention
// epilogue. A: bf16 [M,K] row-major. B: fp32 [K,N] (weights, converted during
// staging). C written as bf16 Hout; a_src/a_dst from fp32 accumulators.
// LDS layout: 8-elem (16B) granules, granule index XOR'd with (row&7) to kill
// bank conflicts on the stride-128B fragment reads.
// Fragment layouts (gfx950, 16x16x32): A: row=lane&15, k=(lane>>4)*8+j;
// B: col=lane&15, k likewise; C/D: col=lane&15, row=(lane>>4)*4+reg.
// ---------------------------------------------------------------------------
template <int HEADS_T>
__global__ __launch_bounds__(256) void mfma_gemm_attn(
    const unsigned short* __restrict__ A, const float* __restrict__ B,
    const float* __restrict__ att_src, const float* __restrict__ att_dst,
    unsigned short* __restrict__ Hout, float* __restrict__ a_src,
    float* __restrict__ a_dst, int M, int N, int K) {
  __shared__ unsigned short As[64 * 64];
  __shared__ unsigned short Bs[64 * 64];  // transposed: [n][k] granules
  const int t = threadIdx.x;
  const int wid = t >> 6, lane = t & 63;
  const int lg = lane >> 4, li = lane & 15;
  const int bm = blockIdx.x * 64, bn = blockIdx.y * 64;
  const int head = blockIdx.y;

  facc4 acc[4];
#pragma unroll
  for (int fn = 0; fn < 4; ++fn) acc[fn] = (facc4)(0.f);

  const int ktiles = K >> 6;
  for (int kt = 0; kt < ktiles; ++kt) {
    // stage A (bf16): 2 passes x 256 threads x 16B. flat = [64 rows][8 gran]
#pragma unroll
    for (int p = 0; p < 2; ++p) {
      int flat = t + p * 256;
      int row = flat >> 3, g = flat & 7;
      int gr = bm + row;
      uint4 v = make_uint4(0, 0, 0, 0);
      if (gr < M)
        v = *reinterpret_cast<const uint4*>(&A[(size_t)gr * K + kt * 64 + g * 8]);
      *reinterpret_cast<uint4*>(&As[row * 64 + ((g ^ (row & 7)) << 3)]) = v;
    }
    // stage B (fp32 -> bf16, transposed): 4 passes. flat = [16 kg4][64 n]
#pragma unroll
    for (int p = 0; p < 4; ++p) {
      int flat = t + p * 256;
      int n = flat & 63, kg = flat >> 6;
      unsigned short q[4];
#pragma unroll
      for (int i = 0; i < 4; ++i)
        q[i] = __bfloat16_as_ushort(__float2bfloat16(
            B[(size_t)(kt * 64 + kg * 4 + i) * N + bn + n]));
      int g = kg >> 1, half = kg & 1;
      *reinterpret_cast<ushort4*>(
          &Bs[n * 64 + ((g ^ (n & 7)) << 3) + half * 4]) =
          *reinterpret_cast<const ushort4*>(q);
    }
    __syncthreads();
#pragma unroll
    for (int ks = 0; ks < 2; ++ks) {
      int arow = wid * 16 + li;
      int gk = ks * 4 + lg;
      bfrag8 a = *reinterpret_cast<const bfrag8*>(
          &As[arow * 64 + ((gk ^ (arow & 7)) << 3)]);
#pragma unroll
      for (int fn = 0; fn < 4; ++fn) {
        int col = fn * 16 + li;
        bfrag8 b = *reinterpret_cast<const bfrag8*>(
            &Bs[col * 64 + ((gk ^ (col & 7)) << 3)]);
        acc[fn] =
            __builtin_amdgcn_mfma_f32_16x16x32_bf16(a, b, acc[fn], 0, 0, 0);
      }
    }
    __syncthreads();
  }

  // Epilogue: attention dots from fp32 acc + bf16 H store.
  float s_att[4], d_att[4];
#pragma unroll
  for (int fn = 0; fn < 4; ++fn) {
    s_att[fn] = att_src[head * 64 + fn * 16 + li];
    d_att[fn] = att_dst[head * 64 + fn * 16 + li];
  }
#pragma unroll
  for (int reg = 0; reg < 4; ++reg) {
    int row = bm + wid * 16 + lg * 4 + reg;
    float ps = 0.f, pd = 0.f;
#pragma unroll
    for (int fn = 0; fn < 4; ++fn) {
      float c = acc[fn][reg];
      ps += c * s_att[fn];
      pd += c * d_att[fn];
    }
#pragma unroll
    for (int m = 1; m < 16; m <<= 1) {
      ps += __shfl_xor(ps, m);
      pd += __shfl_xor(pd, m);
    }
    if (row < M) {
#pragma unroll
      for (int fn = 0; fn < 4; ++fn)
        Hout[(size_t)row * N + bn + fn * 16 + li] =
            __bfloat16_as_ushort(__float2bfloat16(acc[fn][reg]));
      if (li == 0) {
        a_src[(size_t)row * HEADS_T + head] = ps;
        a_dst[(size_t)row * HEADS_T + head] = pd;
      }
    }
  }
}

// ---------------------------------------------------------------------------
// CSR build: histogram -> 3-stage hierarchical scan -> scatter.
// ---------------------------------------------------------------------------
__global__ void hist_kernel(const int* __restrict__ dst, int E,
                            int* __restrict__ deg) {
  int e = blockIdx.x * blockDim.x + threadIdx.x;
  if (e < E) atomicAdd(&deg[dst[e]], 1);
}

__global__ __launch_bounds__(256) void scan_partial_kernel(
    const int* __restrict__ deg, int n, int* __restrict__ partials) {
  __shared__ int sm[256];
  int t = threadIdx.x;
  int i = blockIdx.x * 256 + t;
  sm[t] = (i < n) ? deg[i] : 0;
  __syncthreads();
  for (int off = 128; off > 0; off >>= 1) {
    if (t < off) sm[t] += sm[t + off];
    __syncthreads();
  }
  if (t == 0) partials[blockIdx.x] = sm[0];
}

__global__ __launch_bounds__(256) void scan_base_kernel(
    const int* __restrict__ partials, int nb, int* __restrict__ base) {
  __shared__ int sm[256];
  int t = threadIdx.x;
  int v = (t < nb) ? partials[t] : 0;
  sm[t] = v;
  __syncthreads();
  for (int off = 1; off < 256; off <<= 1) {
    int u = (t >= off) ? sm[t - off] : 0;
    __syncthreads();
    sm[t] += u;
    __syncthreads();
  }
  if (t < nb) base[t] = sm[t] - v;  // exclusive prefix
}

__global__ __launch_bounds__(256) void scan_expand_kernel(
    const int* __restrict__ deg, int n, const int* __restrict__ base,
    int* __restrict__ offsets, int* __restrict__ cursor) {
  __shared__ int sm[256];
  int t = threadIdx.x;
  int i = blockIdx.x * 256 + t;
  int v = (i < n) ? deg[i] : 0;
  sm[t] = v;
  __syncthreads();
  for (int off = 1; off < 256; off <<= 1) {
    int u = (t >= off) ? sm[t - off] : 0;
    __syncthreads();
    sm[t] += u;
    __syncthreads();
  }
  int excl = sm[t] - v + base[blockIdx.x];
  if (i < n) {
    offsets[i] = excl;
    cursor[i] = excl;
  }
}

__global__ void scatter_kernel(const int* __restrict__ src,
                               const int* __restrict__ dst, int E,
                               int* __restrict__ cursor,
                               int* __restrict__ ssrc) {
  int e = blockIdx.x * blockDim.x + threadIdx.x;
  if (e < E) {
    int d = dst[e];
    int pos = atomicAdd(&cursor[d], 1);
    ssrc[pos] = src[e];
  }
}

// ---------------------------------------------------------------------------
// Layer-1 aggregation: one wave per dst node; direct exp (|e| small).
// Branchless software pipeline: ssrc 4 deep, a_src/h 2 deep (named regs).
// Writes hact as bf16 (+bias+ELU). Lane l -> channels 4l..4l+3, head=l>>4.
// ---------------------------------------------------------------------------
__global__ __launch_bounds__(256) void agg1_kernel(
    const unsigned short* __restrict__ h1, const float* __restrict__ a_src,
    const float* __restrict__ a_dst, const int* __restrict__ offsets,
    const int* __restrict__ deg, const int* __restrict__ ssrc,
    const float* __restrict__ bias, unsigned short* __restrict__ out,
    int n_nodes) {
  int wave = (int)((blockIdx.x * blockDim.x + threadIdx.x) >> 6);
  int lane = threadIdx.x & 63;
  if (wave >= n_nodes) return;
  int head = lane >> 4;
  int start = offsets[wave];
  int cnt = deg[wave];  // >= 1 (self-loop)
  int last = cnt - 1;
  float ad = a_dst[wave * 4 + head];
  float l = 0.f, a0 = 0.f, a1 = 0.f, a2 = 0.f, a3 = 0.f;

  int sA = ssrc[start];
  int sB = ssrc[start + min(1, last)];
  int sC = ssrc[start + min(2, last)];
  int sD = ssrc[start + min(3, last)];
  float asA = a_src[sA * 4 + head];
  float asB = a_src[sB * 4 + head];
  ushort4 hA = *reinterpret_cast<const ushort4*>(&h1[(size_t)sA * 256 + lane * 4]);
  ushort4 hB = *reinterpret_cast<const ushort4*>(&h1[(size_t)sB * 256 + lane * 4]);

  for (int j = 0; j < cnt; ++j) {
    int sE = ssrc[start + min(j + 4, last)];
    float asC = a_src[sC * 4 + head];
    ushort4 hC =
        *reinterpret_cast<const ushort4*>(&h1[(size_t)sC * 256 + lane * 4]);
    float e = asA + ad;
    e = (e > 0.f) ? e : NEG_SLOPE * e;
    float p = __expf(e);
    l += p;
    a0 += p * bf16u_to_f(hA.x);
    a1 += p * bf16u_to_f(hA.y);
    a2 += p * bf16u_to_f(hA.z);
    a3 += p * bf16u_to_f(hA.w);
    sA = sB; sB = sC; sC = sD; sD = sE;
    asA = asB; asB = asC;
    hA = hB; hB = hC;
  }
  float inv = 1.0f / l;
  int col = lane * 4;
  float4 b4 = *reinterpret_cast<const float4*>(&bias[col]);
  float o0 = a0 * inv + b4.x;
  float o1 = a1 * inv + b4.y;
  float o2 = a2 * inv + b4.z;
  float o3 = a3 * inv + b4.w;
  o0 = o0 > 0.f ? o0 : __expf(o0) - 1.f;
  o1 = o1 > 0.f ? o1 : __expf(o1) - 1.f;
  o2 = o2 > 0.f ? o2 : __expf(o2) - 1.f;
  o3 = o3 > 0.f ? o3 : __expf(o3) - 1.f;
  unsigned short q[4];
  q[0] = __bfloat16_as_ushort(__float2bfloat16(o0));
  q[1] = __bfloat16_as_ushort(__float2bfloat16(o1));
  q[2] = __bfloat16_as_ushort(__float2bfloat16(o2));
  q[3] = __bfloat16_as_ushort(__float2bfloat16(o3));
  *reinterpret_cast<ushort4*>(&out[(size_t)wave * 256 + col]) =
      *reinterpret_cast<const ushort4*>(q);
}

// Layer-2 aggregation: one wave per node, lane = channel; same pipeline.
__global__ __launch_bounds__(256) void agg2_kernel(
    const unsigned short* __restrict__ h2, const float* __restrict__ a_src,
    const float* __restrict__ a_dst, const int* __restrict__ offsets,
    const int* __restrict__ deg, const int* __restrict__ ssrc,
    const float* __restrict__ bias, float* __restrict__ out, int n_nodes) {
  int wave = (int)((blockIdx.x * blockDim.x + threadIdx.x) >> 6);
  int lane = threadIdx.x & 63;
  if (wave >= n_nodes) return;
  int start = offsets[wave];
  int cnt = deg[wave];
  int last = cnt - 1;
  float ad = a_dst[wave];
  float l = 0.f, acc = 0.f;

  int sA = ssrc[start];
  int sB = ssrc[start + min(1, last)];
  int sC = ssrc[start + min(2, last)];
  int sD = ssrc[start + min(3, last)];
  float asA = a_src[sA];
  float asB = a_src[sB];
  unsigned short hA = h2[(size_t)sA * 64 + lane];
  unsigned short hB = h2[(size_t)sB * 64 + lane];

  for (int j = 0; j < cnt; ++j) {
    int sE = ssrc[start + min(j + 4, last)];
    float asC = a_src[sC];
    unsigned short hC = h2[(size_t)sC * 64 + lane];
    float e = asA + ad;
    e = (e > 0.f) ? e : NEG_SLOPE * e;
    float p = __expf(e);
    l += p;
    acc += p * bf16u_to_f(hA);
    sA = sB; sB = sC; sC = sD; sD = sE;
    asA = asB; asB = asC;
    hA = hB; hB = hC;
  }
  out[(size_t)wave * 64 + lane] = acc / l + bias[lane];
}

// ---------------------------------------------------------------------------
extern "C" void kernel_launch(void* const* d_in, const int* in_sizes, int n_in,
                              void* d_out, int out_size, void* d_ws,
                              size_t ws_size, hipStream_t stream) {
  const float* x = (const float*)d_in[0];
  const int* edge_index = (const int*)d_in[1];
  const float* W1 = (const float*)d_in[2];
  const float* att_src1 = (const float*)d_in[3];
  const float* att_dst1 = (const float*)d_in[4];
  const float* b1 = (const float*)d_in[5];
  const float* W2 = (const float*)d_in[6];
  const float* att_src2 = (const float*)d_in[7];
  const float* att_dst2 = (const float*)d_in[8];
  const float* b2 = (const float*)d_in[9];

  const int n = in_sizes[0] / IN_C;  // 50000
  const int E = in_sizes[1] / 2;     // 850000
  const int* src = edge_index;
  const int* dst = edge_index + E;
  const int nb = (n + 255) / 256;

  char* ws = (char*)d_ws;
  size_t off = 0;
  auto carve = [&](size_t bytes) -> void* {
    void* p = ws + off;
    off = (off + bytes + 255) & ~(size_t)255;
    return p;
  };
  unsigned short* xb = (unsigned short*)carve((size_t)n * IN_C * 2);
  unsigned short* h1b = (unsigned short*)carve((size_t)n * 256 * 2);
  unsigned short* hact = (unsigned short*)carve((size_t)n * 256 * 2);
  unsigned short* h2b = (unsigned short*)carve((size_t)n * 64 * 2);
  float* as1 = (float*)carve((size_t)n * 4 * 4);
  float* ad1 = (float*)carve((size_t)n * 4 * 4);
  float* as2 = (float*)carve((size_t)n * 4);
  float* ad2 = (float*)carve((size_t)n * 4);
  int* deg = (int*)carve((size_t)n * 4);
  int* offsets = (int*)carve((size_t)n * 4);
  int* cursor = (int*)carve((size_t)n * 4);
  int* ssrc = (int*)carve((size_t)E * 4);
  int* partials = (int*)carve((size_t)nb * 4);
  int* base = (int*)carve((size_t)nb * 4);

  hipMemsetAsync(deg, 0, (size_t)n * 4, stream);

  // x -> bf16
  {
    int n8 = n * IN_C / 8;
    cvt_bf16_kernel<<<(n8 + 255) / 256, 256, 0, stream>>>(x, xb, n8);
  }
  // GEMM1 + attn1 fused (MFMA): h1b = bf16(x) @ bf16(W1)
  {
    dim3 g((n + 63) / 64, (HEADS * HID) / 64);
    mfma_gemm_attn<HEADS><<<g, 256, 0, stream>>>(
        xb, W1, att_src1, att_dst1, h1b, as1, ad1, n, HEADS * HID, IN_C);
  }
  // CSR build
  hist_kernel<<<(E + 255) / 256, 256, 0, stream>>>(dst, E, deg);
  scan_partial_kernel<<<nb, 256, 0, stream>>>(deg, n, partials);
  scan_base_kernel<<<1, 256, 0, stream>>>(partials, nb, base);
  scan_expand_kernel<<<nb, 256, 0, stream>>>(deg, n, base, offsets, cursor);
  scatter_kernel<<<(E + 255) / 256, 256, 0, stream>>>(src, dst, E, cursor, ssrc);
  // aggregation layer 1 (+bias+ELU) -> hact (bf16)
  agg1_kernel<<<(n * 64 + 255) / 256, 256, 0, stream>>>(h1b, as1, ad1, offsets,
                                                        deg, ssrc, b1, hact, n);
  // GEMM2 + attn2 fused (MFMA): h2b = hact @ bf16(W2)
  {
    dim3 g((n + 63) / 64, OUT_C / 64);
    mfma_gemm_attn<1><<<g, 256, 0, stream>>>(
        hact, W2, att_src2, att_dst2, h2b, as2, ad2, n, OUT_C, HEADS * HID);
  }
  // aggregation layer 2 (+bias) -> d_out
  agg2_kernel<<<(n * 64 + 255) / 256, 256, 0, stream>>>(
      h2b, as2, ad2, offsets, deg, ssrc, b2, (float*)d_out, n);
}

// Round 4
// 330.730 us; speedup vs baseline: 1.8349x; 1.2303x over previous
//
#include <hip/hip_runtime.h>
#include <hip/hip_bf16.h>

#define IN_C 128
#define HID 64
#define HEADS 4
#define OUT_C 64
#define NEG_SLOPE 0.2f

typedef __attribute__((ext_vector_type(8))) short bfrag8;   // 8 bf16 (4 VGPR)
typedef __attribute__((ext_vector_type(4))) float facc4;    // mfma C/D

__device__ __forceinline__ float bf16u_to_f(unsigned short u) {
  return __uint_as_float(((unsigned)u) << 16);
}

// ---------------------------------------------------------------------------
// x (fp32) -> bf16, 8 elems/thread.
// ---------------------------------------------------------------------------
__global__ __launch_bounds__(256) void cvt_bf16_kernel(
    const float* __restrict__ in, unsigned short* __restrict__ out, int n8) {
  int i = blockIdx.x * blockDim.x + threadIdx.x;
  if (i >= n8) return;
  float4 v0 = *reinterpret_cast<const float4*>(&in[(size_t)i * 8]);
  float4 v1 = *reinterpret_cast<const float4*>(&in[(size_t)i * 8 + 4]);
  unsigned short q[8];
  q[0] = __bfloat16_as_ushort(__float2bfloat16(v0.x));
  q[1] = __bfloat16_as_ushort(__float2bfloat16(v0.y));
  q[2] = __bfloat16_as_ushort(__float2bfloat16(v0.z));
  q[3] = __bfloat16_as_ushort(__float2bfloat16(v0.w));
  q[4] = __bfloat16_as_ushort(__float2bfloat16(v1.x));
  q[5] = __bfloat16_as_ushort(__float2bfloat16(v1.y));
  q[6] = __bfloat16_as_ushort(__float2bfloat16(v1.z));
  q[7] = __bfloat16_as_ushort(__float2bfloat16(v1.w));
  *reinterpret_cast<uint4*>(&out[(size_t)i * 8]) =
      *reinterpret_cast<const uint4*>(q);
}

// ---------------------------------------------------------------------------
// MFMA bf16 GEMM (64x64x64 tile, 4 waves, 16x16x32 mfma) + fused attention
// epilogue (unchanged from R3 -- verified).
// ---------------------------------------------------------------------------
template <int HEADS_T>
__global__ __launch_bounds__(256) void mfma_gemm_attn(
    const unsigned short* __restrict__ A, const float* __restrict__ B,
    const float* __restrict__ att_src, const float* __restrict__ att_dst,
    unsigned short* __restrict__ Hout, float* __restrict__ a_src,
    float* __restrict__ a_dst, int M, int N, int K) {
  __shared__ unsigned short As[64 * 64];
  __shared__ unsigned short Bs[64 * 64];  // transposed: [n][k] granules
  const int t = threadIdx.x;
  const int wid = t >> 6, lane = t & 63;
  const int lg = lane >> 4, li = lane & 15;
  const int bm = blockIdx.x * 64, bn = blockIdx.y * 64;
  const int head = blockIdx.y;

  facc4 acc[4];
#pragma unroll
  for (int fn = 0; fn < 4; ++fn) acc[fn] = (facc4)(0.f);

  const int ktiles = K >> 6;
  for (int kt = 0; kt < ktiles; ++kt) {
#pragma unroll
    for (int p = 0; p < 2; ++p) {
      int flat = t + p * 256;
      int row = flat >> 3, g = flat & 7;
      int gr = bm + row;
      uint4 v = make_uint4(0, 0, 0, 0);
      if (gr < M)
        v = *reinterpret_cast<const uint4*>(&A[(size_t)gr * K + kt * 64 + g * 8]);
      *reinterpret_cast<uint4*>(&As[row * 64 + ((g ^ (row & 7)) << 3)]) = v;
    }
#pragma unroll
    for (int p = 0; p < 4; ++p) {
      int flat = t + p * 256;
      int n = flat & 63, kg = flat >> 6;
      unsigned short q[4];
#pragma unroll
      for (int i = 0; i < 4; ++i)
        q[i] = __bfloat16_as_ushort(__float2bfloat16(
            B[(size_t)(kt * 64 + kg * 4 + i) * N + bn + n]));
      int g = kg >> 1, half = kg & 1;
      *reinterpret_cast<ushort4*>(
          &Bs[n * 64 + ((g ^ (n & 7)) << 3) + half * 4]) =
          *reinterpret_cast<const ushort4*>(q);
    }
    __syncthreads();
#pragma unroll
    for (int ks = 0; ks < 2; ++ks) {
      int arow = wid * 16 + li;
      int gk = ks * 4 + lg;
      bfrag8 a = *reinterpret_cast<const bfrag8*>(
          &As[arow * 64 + ((gk ^ (arow & 7)) << 3)]);
#pragma unroll
      for (int fn = 0; fn < 4; ++fn) {
        int col = fn * 16 + li;
        bfrag8 b = *reinterpret_cast<const bfrag8*>(
            &Bs[col * 64 + ((gk ^ (col & 7)) << 3)]);
        acc[fn] =
            __builtin_amdgcn_mfma_f32_16x16x32_bf16(a, b, acc[fn], 0, 0, 0);
      }
    }
    __syncthreads();
  }

  float s_att[4], d_att[4];
#pragma unroll
  for (int fn = 0; fn < 4; ++fn) {
    s_att[fn] = att_src[head * 64 + fn * 16 + li];
    d_att[fn] = att_dst[head * 64 + fn * 16 + li];
  }
#pragma unroll
  for (int reg = 0; reg < 4; ++reg) {
    int row = bm + wid * 16 + lg * 4 + reg;
    float ps = 0.f, pd = 0.f;
#pragma unroll
    for (int fn = 0; fn < 4; ++fn) {
      float c = acc[fn][reg];
      ps += c * s_att[fn];
      pd += c * d_att[fn];
    }
#pragma unroll
    for (int m = 1; m < 16; m <<= 1) {
      ps += __shfl_xor(ps, m);
      pd += __shfl_xor(pd, m);
    }
    if (row < M) {
#pragma unroll
      for (int fn = 0; fn < 4; ++fn)
        Hout[(size_t)row * N + bn + fn * 16 + li] =
            __bfloat16_as_ushort(__float2bfloat16(acc[fn][reg]));
      if (li == 0) {
        a_src[(size_t)row * HEADS_T + head] = ps;
        a_dst[(size_t)row * HEADS_T + head] = pd;
      }
    }
  }
}

// ---------------------------------------------------------------------------
// CSR build with 4-padded segments.
// ---------------------------------------------------------------------------
__global__ void hist_kernel(const int* __restrict__ dst, int E,
                            int* __restrict__ deg) {
  int e = blockIdx.x * blockDim.x + threadIdx.x;
  if (e < E) atomicAdd(&deg[dst[e]], 1);
}

__device__ __forceinline__ int pad4(int d) { return (d + 3) & ~3; }

__global__ __launch_bounds__(256) void scan_partial_kernel(
    const int* __restrict__ deg, int n, int* __restrict__ partials) {
  __shared__ int sm[256];
  int t = threadIdx.x;
  int i = blockIdx.x * 256 + t;
  sm[t] = (i < n) ? pad4(deg[i]) : 0;
  __syncthreads();
  for (int off = 128; off > 0; off >>= 1) {
    if (t < off) sm[t] += sm[t + off];
    __syncthreads();
  }
  if (t == 0) partials[blockIdx.x] = sm[0];
}

__global__ __launch_bounds__(256) void scan_base_kernel(
    const int* __restrict__ partials, int nb, int* __restrict__ base) {
  __shared__ int sm[256];
  int t = threadIdx.x;
  int v = (t < nb) ? partials[t] : 0;
  sm[t] = v;
  __syncthreads();
  for (int off = 1; off < 256; off <<= 1) {
    int u = (t >= off) ? sm[t - off] : 0;
    __syncthreads();
    sm[t] += u;
    __syncthreads();
  }
  if (t < nb) base[t] = sm[t] - v;
}

__global__ __launch_bounds__(256) void scan_expand_kernel(
    const int* __restrict__ deg, int n, const int* __restrict__ base,
    int* __restrict__ offsets, int* __restrict__ cursor) {
  __shared__ int sm[256];
  int t = threadIdx.x;
  int i = blockIdx.x * 256 + t;
  int v = (i < n) ? pad4(deg[i]) : 0;
  sm[t] = v;
  __syncthreads();
  for (int off = 1; off < 256; off <<= 1) {
    int u = (t >= off) ? sm[t - off] : 0;
    __syncthreads();
    sm[t] += u;
    __syncthreads();
  }
  int excl = sm[t] - v + base[blockIdx.x];
  if (i < n) {
    offsets[i] = excl;
    cursor[i] = excl;
  }
}

__global__ void scatter_kernel(const int* __restrict__ src,
                               const int* __restrict__ dst, int E,
                               int* __restrict__ cursor,
                               int2* __restrict__ sedge) {
  int e = blockIdx.x * blockDim.x + threadIdx.x;
  if (e < E) {
    int d = dst[e];
    int pos = atomicAdd(&cursor[d], 1);
    sedge[pos] = make_int2(src[e], d);
  }
}

// ---------------------------------------------------------------------------
// Edge-parallel alpha precompute, layer 1 (4 heads). Slot-parallel over the
// padded CSR; pad slots (sedge=-1) get p=0, src=0 (self-neutralizing).
// Writes p1[h][slot] planes + compact ssrc.
// ---------------------------------------------------------------------------
__global__ __launch_bounds__(256) void edge_p1_kernel(
    const int2* __restrict__ sedge, const float* __restrict__ as1,
    const float* __restrict__ ad1, float* __restrict__ p1,
    int* __restrict__ ssrc_c, int stride) {
  int i = blockIdx.x * blockDim.x + threadIdx.x;
  if (i >= stride) return;
  int2 e = sedge[i];
  bool valid = e.x >= 0;
  int s = valid ? e.x : 0;
  int d = valid ? e.y : 0;
  float4 a4 = *reinterpret_cast<const float4*>(&as1[s * 4]);
  float4 b4 = *reinterpret_cast<const float4*>(&ad1[d * 4]);
  float v[4] = {a4.x + b4.x, a4.y + b4.y, a4.z + b4.z, a4.w + b4.w};
#pragma unroll
  for (int h = 0; h < 4; ++h) {
    float x = v[h];
    x = (x > 0.f) ? x : NEG_SLOPE * x;
    float p = __expf(x);
    p1[(size_t)h * stride + i] = valid ? p : 0.f;
  }
  ssrc_c[i] = s;
}

// Layer 2: single head.
__global__ __launch_bounds__(256) void edge_p2_kernel(
    const int2* __restrict__ sedge, const float* __restrict__ as2,
    const float* __restrict__ ad2, float* __restrict__ p2, int stride) {
  int i = blockIdx.x * blockDim.x + threadIdx.x;
  if (i >= stride) return;
  int2 e = sedge[i];
  bool valid = e.x >= 0;
  int s = valid ? e.x : 0;
  int d = valid ? e.y : 0;
  float x = as2[s] + ad2[d];
  x = (x > 0.f) ? x : NEG_SLOPE * x;
  float p = __expf(x);
  p2[i] = valid ? p : 0.f;
}

// ---------------------------------------------------------------------------
// Layer-1 aggregation: one wave per dst node, gather-only loop over groups of
// 4 edges. 3-group S queue + 8-edge H queue in named registers, aligned int4 /
// float4 linear loads. Lane l -> channels 4l..4l+3, head=l>>4.
// ---------------------------------------------------------------------------
__global__ __launch_bounds__(256) void agg1_kernel(
    const unsigned short* __restrict__ h1, const float* __restrict__ p1,
    const int* __restrict__ ssrc_c, const int* __restrict__ offsets,
    const int* __restrict__ deg, const float* __restrict__ bias,
    unsigned short* __restrict__ out, int n_nodes, int stride) {
  int wave = (int)((blockIdx.x * blockDim.x + threadIdx.x) >> 6);
  int lane = threadIdx.x & 63;
  if (wave >= n_nodes) return;
  int head = lane >> 4;
  int off = offsets[wave];
  int cnt = deg[wave];  // >= 1 (self-loop)
  int g4 = (cnt + 3) >> 2;
  int last = g4 - 1;
  const int* S_ = ssrc_c + off;
  const float* P_ = p1 + (size_t)head * stride + off;

  auto ldS = [&](int g) {
    return *reinterpret_cast<const int4*>(S_ + min(g, last) * 4);
  };
  auto ldP = [&](int g) {
    return *reinterpret_cast<const float4*>(P_ + min(g, last) * 4);
  };
  auto gat = [&](int s) {
    return *reinterpret_cast<const ushort4*>(&h1[(size_t)s * 256 + lane * 4]);
  };

  int4 S0 = ldS(0), S1 = ldS(1), S2 = ldS(2);
  float4 P0 = ldP(0), P1 = ldP(1);
  ushort4 H0 = gat(S0.x), H1 = gat(S0.y), H2 = gat(S0.z), H3 = gat(S0.w);
  ushort4 H4 = gat(S1.x), H5 = gat(S1.y), H6 = gat(S1.z), H7 = gat(S1.w);

  float l = 0.f, a0 = 0.f, a1 = 0.f, a2 = 0.f, a3 = 0.f;
  for (int j = 0; j <= last; ++j) {
    int4 S3 = ldS(j + 3);
    float4 P2 = ldP(j + 2);
    l += P0.x + P0.y + P0.z + P0.w;
    a0 += P0.x * bf16u_to_f(H0.x) + P0.y * bf16u_to_f(H1.x) +
          P0.z * bf16u_to_f(H2.x) + P0.w * bf16u_to_f(H3.x);
    a1 += P0.x * bf16u_to_f(H0.y) + P0.y * bf16u_to_f(H1.y) +
          P0.z * bf16u_to_f(H2.y) + P0.w * bf16u_to_f(H3.y);
    a2 += P0.x * bf16u_to_f(H0.z) + P0.y * bf16u_to_f(H1.z) +
          P0.z * bf16u_to_f(H2.z) + P0.w * bf16u_to_f(H3.z);
    a3 += P0.x * bf16u_to_f(H0.w) + P0.y * bf16u_to_f(H1.w) +
          P0.z * bf16u_to_f(H2.w) + P0.w * bf16u_to_f(H3.w);
    H0 = H4; H1 = H5; H2 = H6; H3 = H7;
    H4 = gat(S2.x); H5 = gat(S2.y); H6 = gat(S2.z); H7 = gat(S2.w);
    S0 = S1; S1 = S2; S2 = S3;
    P0 = P1; P1 = P2;
  }
  float inv = 1.0f / l;
  int col = lane * 4;
  float4 b4 = *reinterpret_cast<const float4*>(&bias[col]);
  float o0 = a0 * inv + b4.x;
  float o1 = a1 * inv + b4.y;
  float o2 = a2 * inv + b4.z;
  float o3 = a3 * inv + b4.w;
  o0 = o0 > 0.f ? o0 : __expf(o0) - 1.f;
  o1 = o1 > 0.f ? o1 : __expf(o1) - 1.f;
  o2 = o2 > 0.f ? o2 : __expf(o2) - 1.f;
  o3 = o3 > 0.f ? o3 : __expf(o3) - 1.f;
  unsigned short q[4];
  q[0] = __bfloat16_as_ushort(__float2bfloat16(o0));
  q[1] = __bfloat16_as_ushort(__float2bfloat16(o1));
  q[2] = __bfloat16_as_ushort(__float2bfloat16(o2));
  q[3] = __bfloat16_as_ushort(__float2bfloat16(o3));
  *reinterpret_cast<ushort4*>(&out[(size_t)wave * 256 + col]) =
      *reinterpret_cast<const ushort4*>(q);
}

// Layer-2 aggregation: same structure, lane = channel (2B gathers).
__global__ __launch_bounds__(256) void agg2_kernel(
    const unsigned short* __restrict__ h2, const float* __restrict__ p2,
    const int* __restrict__ ssrc_c, const int* __restrict__ offsets,
    const int* __restrict__ deg, const float* __restrict__ bias,
    float* __restrict__ out, int n_nodes) {
  int wave = (int)((blockIdx.x * blockDim.x + threadIdx.x) >> 6);
  int lane = threadIdx.x & 63;
  if (wave >= n_nodes) return;
  int off = offsets[wave];
  int cnt = deg[wave];
  int g4 = (cnt + 3) >> 2;
  int last = g4 - 1;
  const int* S_ = ssrc_c + off;
  const float* P_ = p2 + off;

  auto ldS = [&](int g) {
    return *reinterpret_cast<const int4*>(S_ + min(g, last) * 4);
  };
  auto ldP = [&](int g) {
    return *reinterpret_cast<const float4*>(P_ + min(g, last) * 4);
  };
  auto gat = [&](int s) { return h2[(size_t)s * 64 + lane]; };

  int4 S0 = ldS(0), S1 = ldS(1), S2 = ldS(2);
  float4 P0 = ldP(0), P1 = ldP(1);
  unsigned short H0 = gat(S0.x), H1 = gat(S0.y), H2 = gat(S0.z), H3 = gat(S0.w);
  unsigned short H4 = gat(S1.x), H5 = gat(S1.y), H6 = gat(S1.z), H7 = gat(S1.w);

  float l = 0.f, acc = 0.f;
  for (int j = 0; j <= last; ++j) {
    int4 S3 = ldS(j + 3);
    float4 P2 = ldP(j + 2);
    l += P0.x + P0.y + P0.z + P0.w;
    acc += P0.x * bf16u_to_f(H0) + P0.y * bf16u_to_f(H1) +
           P0.z * bf16u_to_f(H2) + P0.w * bf16u_to_f(H3);
    H0 = H4; H1 = H5; H2 = H6; H3 = H7;
    H4 = gat(S2.x); H5 = gat(S2.y); H6 = gat(S2.z); H7 = gat(S2.w);
    S0 = S1; S1 = S2; S2 = S3;
    P0 = P1; P1 = P2;
  }
  out[(size_t)wave * 64 + lane] = acc / l + bias[lane];
}

// ---------------------------------------------------------------------------
extern "C" void kernel_launch(void* const* d_in, const int* in_sizes, int n_in,
                              void* d_out, int out_size, void* d_ws,
                              size_t ws_size, hipStream_t stream) {
  const float* x = (const float*)d_in[0];
  const int* edge_index = (const int*)d_in[1];
  const float* W1 = (const float*)d_in[2];
  const float* att_src1 = (const float*)d_in[3];
  const float* att_dst1 = (const float*)d_in[4];
  const float* b1 = (const float*)d_in[5];
  const float* W2 = (const float*)d_in[6];
  const float* att_src2 = (const float*)d_in[7];
  const float* att_dst2 = (const float*)d_in[8];
  const float* b2 = (const float*)d_in[9];

  const int n = in_sizes[0] / IN_C;  // 50000
  const int E = in_sizes[1] / 2;     // 850000
  const int* src = edge_index;
  const int* dst = edge_index + E;
  const int nb = (n + 255) / 256;
  const int stride = (E + 4 * n + 3) & ~3;  // padded-slot bound, %4==0

  char* ws = (char*)d_ws;
  size_t off = 0;
  auto carve = [&](size_t bytes) -> void* {
    void* p = ws + off;
    off = (off + bytes + 255) & ~(size_t)255;
    return p;
  };
  unsigned short* xb = (unsigned short*)carve((size_t)n * IN_C * 2);
  unsigned short* h1b = (unsigned short*)carve((size_t)n * 256 * 2);
  unsigned short* hact = (unsigned short*)carve((size_t)n * 256 * 2);
  unsigned short* h2b = (unsigned short*)carve((size_t)n * 64 * 2);
  float* as1 = (float*)carve((size_t)n * 4 * 4);
  float* ad1 = (float*)carve((size_t)n * 4 * 4);
  float* as2 = (float*)carve((size_t)n * 4);
  float* ad2 = (float*)carve((size_t)n * 4);
  int* deg = (int*)carve((size_t)n * 4);
  int* offsets = (int*)carve((size_t)n * 4);
  int* cursor = (int*)carve((size_t)n * 4);
  int2* sedge = (int2*)carve((size_t)stride * 8);
  int* ssrc_c = (int*)carve((size_t)stride * 4);
  float* p1 = (float*)carve((size_t)stride * 4 * 4);
  float* p2 = (float*)carve((size_t)stride * 4);
  int* partials = (int*)carve((size_t)nb * 4);
  int* base = (int*)carve((size_t)nb * 4);

  hipMemsetAsync(deg, 0, (size_t)n * 4, stream);
  hipMemsetAsync(sedge, 0xFF, (size_t)stride * 8, stream);

  {
    int n8 = n * IN_C / 8;
    cvt_bf16_kernel<<<(n8 + 255) / 256, 256, 0, stream>>>(x, xb, n8);
  }
  // GEMM1 + attn1 fused (MFMA)
  {
    dim3 g((n + 63) / 64, (HEADS * HID) / 64);
    mfma_gemm_attn<HEADS><<<g, 256, 0, stream>>>(
        xb, W1, att_src1, att_dst1, h1b, as1, ad1, n, HEADS * HID, IN_C);
  }
  // CSR build (padded)
  hist_kernel<<<(E + 255) / 256, 256, 0, stream>>>(dst, E, deg);
  scan_partial_kernel<<<nb, 256, 0, stream>>>(deg, n, partials);
  scan_base_kernel<<<1, 256, 0, stream>>>(partials, nb, base);
  scan_expand_kernel<<<nb, 256, 0, stream>>>(deg, n, base, offsets, cursor);
  scatter_kernel<<<(E + 255) / 256, 256, 0, stream>>>(src, dst, E, cursor,
                                                      sedge);
  // alpha precompute layer 1, then gather-only aggregation
  edge_p1_kernel<<<(stride + 255) / 256, 256, 0, stream>>>(sedge, as1, ad1, p1,
                                                           ssrc_c, stride);
  agg1_kernel<<<(n * 64 + 255) / 256, 256, 0, stream>>>(
      h1b, p1, ssrc_c, offsets, deg, b1, hact, n, stride);
  // GEMM2 + attn2 fused (MFMA)
  {
    dim3 g((n + 63) / 64, OUT_C / 64);
    mfma_gemm_attn<1><<<g, 256, 0, stream>>>(
        hact, W2, att_src2, att_dst2, h2b, as2, ad2, n, OUT_C, HEADS * HID);
  }
  // alpha precompute layer 2, then aggregation -> d_out
  edge_p2_kernel<<<(stride + 255) / 256, 256, 0, stream>>>(sedge, as2, ad2, p2,
                                                           stride);
  agg2_kernel<<<(n * 64 + 255) / 256, 256, 0, stream>>>(
      h2b, p2, ssrc_c, offsets, deg, b2, (float*)d_out, n);
}